// Round 10
// baseline (144.098 us; speedup 1.0000x reference)
//
#include <hip/hip_runtime.h>
#include <math.h>

// Problem constants: B=8, Cin=Cout=64, H=W=96, K=3x3, stride=1, pad=1, dil=1
#define B_    8
#define CIN   64
#define COUT  64
#define H_    96
#define W_    96
#define HW    9216
#define KK    9
#define PIX   64            // output pixels per block
#define NTHR  256
#define BLKS_PER_B 144      // HW / PIX

typedef __attribute__((ext_vector_type(8))) short short8;
typedef __attribute__((ext_vector_type(4))) float floatx4;

static __device__ __forceinline__ unsigned short f2bf(float f) {
    unsigned u = __float_as_uint(f);
    unsigned r = (u + 0x7FFFu + ((u >> 16) & 1u)) >> 16;   // RNE
    return (unsigned short)r;
}

// ---------- merged prep: NCHW->NHWC bf16 transpose of x  +  weight->A-frag ----------
// blocks [0,1152): x transpose; blocks [1152,1170): weight prep.
// xTu row layout: 128 B per hw position = channels 0..63 as bf16 pairs.
// wA frag row for (kstep kap in [0,18), mt, lane): 8 bf16 at ((kap*4+mt)*64+lane)*8
// element j = W[o = mt*16 + (lane&15)][c = (kap&1)*32 + (lane>>4)*8 + j][tap = kap>>1]
__global__ __launch_bounds__(256) void prep_kernel(const float* __restrict__ x,
                                                   const float* __restrict__ w,
                                                   unsigned int* __restrict__ xTu,
                                                   unsigned short* __restrict__ wA) {
    __shared__ float tile[64][65];
    if (blockIdx.x < B_ * BLKS_PER_B) {
        int b   = blockIdx.x / BLKS_PER_B;
        int hw0 = (blockIdx.x % BLKS_PER_B) * 64;
        int lane = threadIdx.x & 63;
        int r    = threadIdx.x >> 6;
        const float* xb = x + (size_t)b * CIN * HW;
        #pragma unroll
        for (int i = 0; i < 16; ++i) {
            int c = r + i * 4;
            tile[c][lane] = xb[(size_t)c * HW + hw0 + lane];          // 256B coalesced
        }
        __syncthreads();
        unsigned int* dst = xTu + ((size_t)b * HW + hw0) * 32;
        int c2 = threadIdx.x & 31;
        int pr = threadIdx.x >> 5;          // 0..7
        #pragma unroll
        for (int i = 0; i < 8; ++i) {
            int p = pr + i * 8;
            unsigned pk = (unsigned)f2bf(tile[2 * c2][p]) |
                          ((unsigned)f2bf(tile[2 * c2 + 1][p]) << 16);
            dst[(size_t)p * 32 + c2] = pk;                            // 128B segments
        }
    } else {
        int gid  = (blockIdx.x - B_ * BLKS_PER_B) * 256 + threadIdx.x;   // [0, 4608)
        int lane = gid & 63;
        int mt   = (gid >> 6) & 3;
        int kap  = gid >> 8;                          // 0..17
        int o    = mt * 16 + (lane & 15);
        int cb   = (kap & 1) * 32 + (lane >> 4) * 8;
        int tap  = kap >> 1;
        short8 v;
        #pragma unroll
        for (int j = 0; j < 8; ++j)
            v[j] = (short)f2bf(w[o * 576 + (cb + j) * 9 + tap]);
        *(short8*)&wA[(size_t)gid * 8] = v;
    }
}

// ---------- main fused MFMA kernel (bilinear folded through MFMA) ----------
// Block = 256 thr = 4 waves, barrier-free: wave wq owns pixels [wq*16,+16) and
// all 64 out-channels. Per tap, instead of computing bilinear samples in VALU:
//   acc[oc][px] = sum_q  w_q[px] * (W x X_q)[oc][px]
// 4 corner-matmuls on RAW bf16 corner rows (B-frag = dwordx4 straight from the
// NHWC xTu: lane -> px=lane&15, kchunk=lane>>4 -- the layout verified in R3-R9),
// then one fp32 scale-accumulate per corner (w_q per-lane scalar). This deletes
// the sampler: no per-channel bilinear, no bf16 repack, no S tile / LDS
// roundtrip; gathers 32 -> 8 per tap (same bytes / cachelines). MFMA x4 (was
// 4.5% utilized -- free). zero4 as MFMA C avoids per-corner zero-init.
// No __syncthreads anywhere (wave-private LDS; intra-wave lgkmcnt ordering).
__global__ __launch_bounds__(256, 3) void deform_mfma_kernel(
    const unsigned int* __restrict__ xTu, const float* __restrict__ offset,
    const float* __restrict__ x2, const float* __restrict__ bias,
    const unsigned short* __restrict__ wA, float* __restrict__ out)
{
    __shared__ float4  awP[KK * PIX];                // 9.2 KB  f32 masked corner products
    __shared__ ushort4 eoS[KK * PIX];                // 4.6 KB  corner positions (y*W+x)

    const int tid  = threadIdx.x;
    const int b    = blockIdx.x & 7;                 // XCD-friendly batch swizzle
    const int pix0 = (blockIdx.x >> 3) * PIX;
    const int lane = tid & 63;
    const int wq   = __builtin_amdgcn_readfirstlane(tid >> 6);

    const float* offb = offset + (size_t)b * (18 * HW);
    const short8* wAv = (const short8*)wA;
    const char*  xbB  = (const char*)xTu + (size_t)b * HW * 128;   // 128 B per hw row

    // ---- per-wave precompute: 9 taps x this wave's 16 pixels (no barrier) ----
    for (int el = lane; el < KK * 16; el += 64) {
        int t  = el >> 4;
        int p  = (wq << 4) + (el & 15);
        int e  = t * 64 + p;
        int hw = pix0 + p;
        int h  = hw / W_;
        int w  = hw - h * W_;
        float offy = offb[(size_t)(2 * t) * HW + hw];
        float offx = offb[(size_t)(2 * t + 1) * HW + hw];
        int ki = t / 3;
        int kj = t - ki * 3;
        float yy = (float)(h - 1 + ki) + offy;
        float xx = (float)(w - 1 + kj) + offx;
        float y0f = floorf(yy), x0f = floorf(xx);
        float wy1 = yy - y0f, wx1 = xx - x0f;
        float wy0 = 1.0f - wy1, wx0 = 1.0f - wx1;
        int y0 = (int)y0f, x0 = (int)x0f;
        int y1 = y0 + 1, x1 = x0 + 1;
        float ay0 = (y0 >= 0 && y0 < H_) ? wy0 : 0.0f;
        float ay1 = (y1 >= 0 && y1 < H_) ? wy1 : 0.0f;
        float ax0 = (x0 >= 0 && x0 < W_) ? wx0 : 0.0f;
        float ax1 = (x1 >= 0 && x1 < W_) ? wx1 : 0.0f;
        int y0c = min(max(y0, 0), H_ - 1), y1c = min(max(y1, 0), H_ - 1);
        int x0c = min(max(x0, 0), W_ - 1), x1c = min(max(x1, 0), W_ - 1);
        awP[e] = make_float4(ay0 * ax0, ay0 * ax1, ay1 * ax0, ay1 * ax1);
        eoS[e] = make_ushort4((unsigned short)(y0c * W_ + x0c),
                              (unsigned short)(y0c * W_ + x1c),
                              (unsigned short)(y1c * W_ + x0c),
                              (unsigned short)(y1c * W_ + x1c));
    }

    floatx4 acc[4];
    #pragma unroll
    for (int mt = 0; mt < 4; ++mt) acc[mt] = (floatx4){0.f, 0.f, 0.f, 0.f};
    const floatx4 zero4 = (floatx4){0.f, 0.f, 0.f, 0.f};

    const int n_  = lane & 15;                 // px within wave's 16 (MFMA n / D col)
    const int h16 = (lane >> 4) * 16;          // byte offset of this lane's k-chunk
    const int pxl = wq * 16 + n_;              // block-local pixel index

    #pragma unroll
    for (int t = 0; t < KK; ++t) {
        // ---- A-frags for tap t: 8 x 16B from L2-hot wA (all waves share) ----
        short8 aA0[4], aA1[4];
        #pragma unroll
        for (int mt = 0; mt < 4; ++mt) {
            aA0[mt] = wAv[(size_t)((t * 2    ) * 4 + mt) * 64 + lane];
            aA1[mt] = wAv[(size_t)((t * 2 + 1) * 4 + mt) * 64 + lane];
        }

        // ---- per-lane corner info for its pixel (wave-private LDS) ----
        ushort4 o4 = eoS[t * 64 + pxl];        // ds_read_b64, 16 addrs/wave
        float4  w4 = awP[t * 64 + pxl];        // ds_read_b128, 16 addrs/wave
        const int   oq[4] = {o4.x, o4.y, o4.z, o4.w};
        const float wc[4] = {w4.x, w4.y, w4.z, w4.w};

        // ---- B-frags: raw bf16 corner rows, 8 x dwordx4 ----
        short8 Blo[4], Bhi[4];
        #pragma unroll
        for (int q = 0; q < 4; ++q) {
            const char* base = xbB + (size_t)oq[q] * 128 + h16;
            Blo[q] = *(const short8*)(base);        // channels  0..31 chunk
            Bhi[q] = *(const short8*)(base + 64);   // channels 32..63 chunk
        }

        // ---- 4 corner-matmuls + fp32 scale-accumulate ----
        #pragma unroll
        for (int q = 0; q < 4; ++q) {
            #pragma unroll
            for (int mt = 0; mt < 4; ++mt) {
                floatx4 d = __builtin_amdgcn_mfma_f32_16x16x32_bf16(aA0[mt], Blo[q], zero4, 0, 0, 0);
                d = __builtin_amdgcn_mfma_f32_16x16x32_bf16(aA1[mt], Bhi[q], d, 0, 0, 0);
                acc[mt][0] = fmaf(wc[q], d[0], acc[mt][0]);
                acc[mt][1] = fmaf(wc[q], d[1], acc[mt][1]);
                acc[mt][2] = fmaf(wc[q], d[2], acc[mt][2]);
                acc[mt][3] = fmaf(wc[q], d[3], acc[mt][3]);
            }
        }
    }

    // ---- epilogue: + bias + x2, clip [0,6] ----
    // C/D layout: col = lane&15 (pixel), row = (lane>>4)*4 + reg (oc within m-tile)
    {
        const int quad4 = (lane >> 4) * 4;
        const size_t hwcol = (size_t)pix0 + wq * 16 + n_;
        #pragma unroll
        for (int mt = 0; mt < 4; ++mt) {
            #pragma unroll
            for (int reg = 0; reg < 4; ++reg) {
                int oc = mt * 16 + quad4 + reg;
                size_t idx = ((size_t)(b * COUT + oc)) * HW + hwcol;
                float r = acc[mt][reg] + bias[oc] + x2[idx];
                r = fminf(fmaxf(r, 0.0f), 6.0f);
                out[idx] = r;
            }
        }
    }
}

// ---------- fallback (NCHW, fp32) if workspace too small ----------
__global__ __launch_bounds__(256, 4) void deform_nchw_kernel(
    const float* __restrict__ x, const float* __restrict__ offset,
    const float* __restrict__ x2, const float* __restrict__ weight,
    const float* __restrict__ bias, float* __restrict__ out)
{
    __shared__ float sT[CIN * PIX];
    __shared__ float ewS[4][KK * PIX];
    __shared__ int   eoS[4][KK * PIX];

    const int tid  = threadIdx.x;
    const int b    = blockIdx.x / BLKS_PER_B;
    const int pix0 = (blockIdx.x % BLKS_PER_B) * PIX;
    const int lane = tid & 63;
    const int wq   = __builtin_amdgcn_readfirstlane(tid >> 6);

    const float* xb   = x + (size_t)b * (CIN * HW);
    const float* offb = offset + (size_t)b * (18 * HW);

    for (int e = tid; e < KK * PIX; e += NTHR) {
        int k  = e >> 6;
        int p  = e & 63;
        int hw = pix0 + p;
        int h  = hw / W_;
        int w  = hw - h * W_;
        float offy = offb[(size_t)(2 * k) * HW + hw];
        float offx = offb[(size_t)(2 * k + 1) * HW + hw];
        int ki = k / 3;
        int kj = k - ki * 3;
        float yy = (float)(h - 1 + ki) + offy;
        float xx = (float)(w - 1 + kj) + offx;
        float y0f = floorf(yy), x0f = floorf(xx);
        float wy1 = yy - y0f, wx1 = xx - x0f;
        float wy0 = 1.0f - wy1, wx0 = 1.0f - wx1;
        int y0 = (int)y0f, x0 = (int)x0f;
        int y1 = y0 + 1, x1 = x0 + 1;
        float vy0 = (y0 >= 0 && y0 < H_) ? 1.0f : 0.0f;
        float vy1 = (y1 >= 0 && y1 < H_) ? 1.0f : 0.0f;
        float vx0 = (x0 >= 0 && x0 < W_) ? 1.0f : 0.0f;
        float vx1 = (x1 >= 0 && x1 < W_) ? 1.0f : 0.0f;
        int y0c = min(max(y0, 0), H_ - 1), y1c = min(max(y1, 0), H_ - 1);
        int x0c = min(max(x0, 0), W_ - 1), x1c = min(max(x1, 0), W_ - 1);
        ewS[0][e] = wy0 * wx0 * vy0 * vx0;
        ewS[1][e] = wy0 * wx1 * vy0 * vx1;
        ewS[2][e] = wy1 * wx0 * vy1 * vx0;
        ewS[3][e] = wy1 * wx1 * vy1 * vx1;
        eoS[0][e] = y0c * W_ + x0c;
        eoS[1][e] = y0c * W_ + x1c;
        eoS[2][e] = y1c * W_ + x0c;
        eoS[3][e] = y1c * W_ + x1c;
    }

    float acc[16];
    #pragma unroll
    for (int i = 0; i < 16; ++i) acc[i] = 0.0f;

    __syncthreads();

    for (int k = 0; k < KK; ++k) {
        {
            const int eb = k * 64 + lane;
            const float w0 = ewS[0][eb], w1 = ewS[1][eb], w2 = ewS[2][eb], w3 = ewS[3][eb];
            const int   o0 = eoS[0][eb], o1 = eoS[1][eb], o2 = eoS[2][eb], o3 = eoS[3][eb];
            const int cg = tid >> 6;
            const float* xc = xb + (size_t)(cg * 16) * HW;
            #pragma unroll
            for (int i = 0; i < 16; ++i) {
                float v = w0 * xc[o0] + w1 * xc[o1] + w2 * xc[o2] + w3 * xc[o3];
                sT[(cg * 16 + i) * 64 + lane] = v;
                xc += HW;
            }
        }
        __syncthreads();
        {
            #pragma unroll 2
            for (int c = 0; c < 64; ++c) {
                float sv = sT[c * 64 + lane];
                #pragma unroll
                for (int oi = 0; oi < 16; ++oi)
                    acc[oi] = fmaf(weight[(wq * 16 + oi) * 576 + c * 9 + k], sv, acc[oi]);
            }
        }
        __syncthreads();
    }

    const size_t obase = ((size_t)b * COUT + wq * 16) * HW + pix0 + lane;
    #pragma unroll
    for (int oi = 0; oi < 16; ++oi) {
        float r = acc[oi] + bias[wq * 16 + oi] + x2[obase + (size_t)oi * HW];
        r = fminf(fmaxf(r, 0.0f), 6.0f);
        out[obase + (size_t)oi * HW] = r;
    }
}

extern "C" void kernel_launch(void* const* d_in, const int* in_sizes, int n_in,
                              void* d_out, int out_size, void* d_ws, size_t ws_size,
                              hipStream_t stream) {
    const float* x      = (const float*)d_in[0];
    const float* offset = (const float*)d_in[1];
    const float* x2     = (const float*)d_in[2];
    const float* weight = (const float*)d_in[3];
    const float* bias   = (const float*)d_in[4];
    float* out          = (float*)d_out;

    const int grid = B_ * BLKS_PER_B;   // 1152 blocks

    const size_t xT_bytes = (size_t)B_ * HW * CIN * sizeof(unsigned short);   // 9.44 MB
    const size_t wA_bytes = (size_t)18 * 4 * 64 * 8 * sizeof(unsigned short); // 73.7 KB

    if (ws_size >= xT_bytes + wA_bytes) {
        unsigned int*   xTu = (unsigned int*)d_ws;
        unsigned short* wA  = (unsigned short*)((char*)d_ws + xT_bytes);
        prep_kernel<<<grid + 18, 256, 0, stream>>>(x, weight, xTu, wA);
        deform_mfma_kernel<<<grid, NTHR, 0, stream>>>(xTu, offset, x2, bias, wA, out);
    } else {
        deform_nchw_kernel<<<grid, NTHR, 0, stream>>>(x, offset, x2, weight, bias, out);
    }
}

// Round 11
// 112.935 us; speedup vs baseline: 1.2759x; 1.2759x over previous
//
#include <hip/hip_runtime.h>
#include <math.h>

// Problem constants: B=8, Cin=Cout=64, H=W=96, K=3x3, stride=1, pad=1, dil=1
#define B_    8
#define CIN   64
#define COUT  64
#define H_    96
#define W_    96
#define HW    9216
#define KK    9
#define PIX   64            // output pixels per block
#define NTHR  256
#define BLKS_PER_B 144      // HW / PIX
#define SP    72            // S row stride in bf16 (144 B: 16B-aligned, 2-way-conflict-free)

typedef __attribute__((ext_vector_type(8))) short short8;
typedef __attribute__((ext_vector_type(4))) float floatx4;

#if __has_builtin(__builtin_amdgcn_fdot2_f32_bf16)
#define HAVE_DOT2 1
typedef __attribute__((ext_vector_type(2))) __bf16 bf16x2;
static __device__ __forceinline__ bf16x2 as_bf16x2(unsigned u) {
    union { unsigned u; bf16x2 v; } c; c.u = u; return c.v;
}
#else
#define HAVE_DOT2 0
#endif

static __device__ __forceinline__ unsigned short f2bf(float f) {
    unsigned u = __float_as_uint(f);
    unsigned r = (u + 0x7FFFu + ((u >> 16) & 1u)) >> 16;   // RNE
    return (unsigned short)r;
}
static __device__ __forceinline__ float bf_lo(unsigned u) { return __uint_as_float(u << 16); }
static __device__ __forceinline__ float bf_hi(unsigned u) { return __uint_as_float(u & 0xFFFF0000u); }

// cheap bf16x2 pack: round-half-away (+0x8000) then splice high halves with one v_perm
static __device__ __forceinline__ unsigned pack_bf2(float vl, float vh) {
    unsigned rl = __float_as_uint(vl) + 0x8000u;
    unsigned rh = __float_as_uint(vh) + 0x8000u;
    return __builtin_amdgcn_perm(rh, rl, 0x07060302u);   // (hi16(rh)<<16)|hi16(rl)
}

// ---------- merged prep: NCHW->NHWC bf16 transpose of x  +  weight->A-frag ----------
// blocks [0,1152): x transpose; blocks [1152,1170): weight prep.
// xTu row layout: 128 B per hw position = channels 0..63 as bf16 pairs.
// wA frag row for (kstep kap in [0,18), wq, lane): 8 bf16 at ((kap*4+wq)*64+lane)*8
__global__ __launch_bounds__(256) void prep_kernel(const float* __restrict__ x,
                                                   const float* __restrict__ w,
                                                   unsigned int* __restrict__ xTu,
                                                   unsigned short* __restrict__ wA) {
    __shared__ float tile[64][65];
    if (blockIdx.x < B_ * BLKS_PER_B) {
        int b   = blockIdx.x / BLKS_PER_B;
        int hw0 = (blockIdx.x % BLKS_PER_B) * 64;
        const float* xb = x + (size_t)b * CIN * HW;
        int lane4 = (threadIdx.x & 15) * 4;      // 4 consecutive hw per thread
        int crow  = threadIdx.x >> 4;            // 0..15
        #pragma unroll
        for (int i = 0; i < 4; ++i) {
            int c = crow + i * 16;
            float4 v = *(const float4*)&xb[(size_t)c * HW + hw0 + lane4];   // 256B/row coalesced
            tile[c][lane4 + 0] = v.x;
            tile[c][lane4 + 1] = v.y;
            tile[c][lane4 + 2] = v.z;
            tile[c][lane4 + 3] = v.w;
        }
        __syncthreads();
        unsigned int* dst = xTu + ((size_t)b * HW + hw0) * 32;
        int c2 = threadIdx.x & 31;
        int pr = threadIdx.x >> 5;          // 0..7
        #pragma unroll
        for (int i = 0; i < 8; ++i) {
            int p = pr + i * 8;
            unsigned pk = (unsigned)f2bf(tile[2 * c2][p]) |
                          ((unsigned)f2bf(tile[2 * c2 + 1][p]) << 16);
            dst[(size_t)p * 32 + c2] = pk;                            // 128B segments
        }
    } else {
        int gid  = (blockIdx.x - B_ * BLKS_PER_B) * 256 + threadIdx.x;   // [0, 4608)
        int lane = gid & 63;
        int wq   = (gid >> 6) & 3;
        int kap  = gid >> 8;                          // 0..17
        int o    = wq * 16 + (lane & 15);
        int cb   = (kap & 1) * 32 + (lane >> 4) * 8;
        int tap  = kap >> 1;
        short8 v;
        #pragma unroll
        for (int j = 0; j < 8; ++j)
            v[j] = (short)f2bf(w[o * 576 + (cb + j) * 9 + tap]);
        *(short8*)&wA[(size_t)gid * 8] = v;
    }
}

// ---- sampler helpers ----
// eoU[e] = { offA, offB }: BYTE offsets of corner rows (y0,xb) and (y1,xb),
// pre-biased +128 (base pointer is xT - 128). x+1 corner = immediate +128:
// valid whenever ax1 != 0 (then x1c = xb+1); weight-0 corners may read
// garbage but stay inside d_ws (256B front pad + wA tail absorb the edges).
static __device__ __forceinline__ void issue_tap_loads(
    const char* __restrict__ xbB, const uint2* eoU,
    int t, int wq, int half, int c4, unsigned (&u)[8][4])
{
    #pragma unroll
    for (int j = 0; j < 8; ++j) {
        int p = wq * 16 + j * 2 + half;
        uint2 o2 = eoU[t * 64 + p];                   // ds_read_b64 broadcast
        const char* pa = xbB + (o2.x + c4);           // 1 v_add each
        const char* pb = xbB + (o2.y + c4);
        u[j][0] = *(const unsigned*)(pa);             // (y0,x0)
        u[j][1] = *(const unsigned*)(pa + 128);       // (y0,x1)  imm offset
        u[j][2] = *(const unsigned*)(pb);             // (y1,x0)
        u[j][3] = *(const unsigned*)(pb + 128);       // (y1,x1)  imm offset
    }
}

#if HAVE_DOT2
// products packed as bf16 pairs: awP[e] = { (w00,w01), (w10,w11) }
static __device__ __forceinline__ void compute_tap(
    const uint2* awP, short* Sbuf, int t, int wq, int half, int c2,
    const unsigned (&u)[8][4])
{
    unsigned int* Su = (unsigned int*)Sbuf;
    #pragma unroll
    for (int j = 0; j < 8; ++j) {
        int p = wq * 16 + j * 2 + half;
        uint2 aw = awP[t * 64 + p];                    // ds_read_b64 broadcast
        unsigned lo01 = __builtin_amdgcn_perm(u[j][1], u[j][0], 0x05040100u);
        unsigned hi01 = __builtin_amdgcn_perm(u[j][1], u[j][0], 0x07060302u);
        unsigned lo23 = __builtin_amdgcn_perm(u[j][3], u[j][2], 0x05040100u);
        unsigned hi23 = __builtin_amdgcn_perm(u[j][3], u[j][2], 0x07060302u);
        float vl = __builtin_amdgcn_fdot2_f32_bf16(as_bf16x2(lo01), as_bf16x2(aw.x), 0.0f, false);
        vl = __builtin_amdgcn_fdot2_f32_bf16(as_bf16x2(lo23), as_bf16x2(aw.y), vl, false);
        float vh = __builtin_amdgcn_fdot2_f32_bf16(as_bf16x2(hi01), as_bf16x2(aw.x), 0.0f, false);
        vh = __builtin_amdgcn_fdot2_f32_bf16(as_bf16x2(hi23), as_bf16x2(aw.y), vh, false);
        Su[p * (SP / 2) + c2] = pack_bf2(vl, vh);
    }
}
#else
static __device__ __forceinline__ void compute_tap(
    const float4* ewP, short* Sbuf, int t, int wq, int half, int c2,
    const unsigned (&u)[8][4])
{
    unsigned int* Su = (unsigned int*)Sbuf;
    #pragma unroll
    for (int j = 0; j < 8; ++j) {
        int p = wq * 16 + j * 2 + half;
        float4 w4 = ewP[t * 64 + p];
        float vl = w4.x * bf_lo(u[j][0]);
        vl = fmaf(w4.y, bf_lo(u[j][1]), vl);
        vl = fmaf(w4.z, bf_lo(u[j][2]), vl);
        vl = fmaf(w4.w, bf_lo(u[j][3]), vl);
        float vh = w4.x * bf_hi(u[j][0]);
        vh = fmaf(w4.y, bf_hi(u[j][1]), vh);
        vh = fmaf(w4.z, bf_hi(u[j][2]), vh);
        vh = fmaf(w4.w, bf_hi(u[j][3]), vh);
        Su[p * (SP / 2) + c2] = pack_bf2(vl, vh);
    }
}
#endif

// ---------- main fused MFMA kernel (best R6 structure + cheap addressing) ----------
// Block = 256 thr = 4 waves, 64 pixels x 64 out-channels of one batch.
// Per tap: [bilinear via perm+dot2, cheap pack -> S (dbuf)] -> barrier ->
// [issue next tap's 32 hoisted gathers + A-frag prefetch, overlap 8 MFMA].
__global__ __launch_bounds__(256, 4) void deform_mfma_kernel(
    const unsigned int* __restrict__ xTu, const float* __restrict__ offset,
    const float* __restrict__ x2, const float* __restrict__ bias,
    const unsigned short* __restrict__ wA, float* __restrict__ out)
{
#if HAVE_DOT2
    __shared__ uint2   awP[KK * PIX];                // 4.6 KB  packed bf16 corner products
#else
    __shared__ float4  awP[KK * PIX];                // 9.2 KB  f32 corner products
#endif
    __shared__ uint2   eoU[KK * PIX];                // 4.6 KB  corner-row byte offsets
    __shared__ __align__(16) short S[2][PIX * SP];   // 18.4 KB double-buffered sample tile

    const int tid  = threadIdx.x;
    const int b    = blockIdx.x & 7;                 // XCD-friendly batch swizzle
    const int pix0 = (blockIdx.x >> 3) * PIX;
    const int lane = tid & 63;
    const int wq   = __builtin_amdgcn_readfirstlane(tid >> 6);

    // biased base: stored offsets carry +128; net address = xT + (row*128 ...)
    const char* xbB = (const char*)xTu + (size_t)b * HW * 128 - 128;
    const float* offb = offset + (size_t)b * (18 * HW);

    const short8* wAv = (const short8*)wA;
    const int abase = wq * 64 + lane;

    // prime tap-0 A-fragment window (L2-hot, shared by all blocks)
    short8 a0 = wAv[abase];                          // channels  0..31 of tap 0
    short8 a1 = wAv[abase + 4 * 64];                 // channels 32..63 of tap 0

    // ---- precompute masked bilinear corner products + row offsets ----
    for (int e = tid; e < KK * PIX; e += NTHR) {
        int k  = e >> 6;
        int p  = e & 63;
        int hw = pix0 + p;
        int h  = hw / W_;
        int w  = hw - h * W_;
        float offy = offb[(size_t)(2 * k) * HW + hw];
        float offx = offb[(size_t)(2 * k + 1) * HW + hw];
        int ki = k / 3;
        int kj = k - ki * 3;
        float yy = (float)(h - 1 + ki) + offy;
        float xx = (float)(w - 1 + kj) + offx;
        float y0f = floorf(yy), x0f = floorf(xx);
        float wy1 = yy - y0f, wx1 = xx - x0f;
        float wy0 = 1.0f - wy1, wx0 = 1.0f - wx1;
        int y0 = (int)y0f, x0 = (int)x0f;
        int y1 = y0 + 1, x1 = x0 + 1;
        float ay0 = (y0 >= 0 && y0 < H_) ? wy0 : 0.0f;
        float ay1 = (y1 >= 0 && y1 < H_) ? wy1 : 0.0f;
        float ax0 = (x0 >= 0 && x0 < W_) ? wx0 : 0.0f;
        float ax1 = (x1 >= 0 && x1 < W_) ? wx1 : 0.0f;
        float w00 = ay0 * ax0, w01 = ay0 * ax1, w10 = ay1 * ax0, w11 = ay1 * ax1;
        int y0c = min(max(y0, 0), H_ - 1), y1c = min(max(y1, 0), H_ - 1);
        int xb_ = min(max(x0, -1), W_ - 1);          // -1 allowed: x1=0 corner stays exact
#if HAVE_DOT2
        awP[e] = make_uint2((unsigned)f2bf(w00) | ((unsigned)f2bf(w01) << 16),
                            (unsigned)f2bf(w10) | ((unsigned)f2bf(w11) << 16));
#else
        awP[e] = make_float4(w00, w01, w10, w11);
#endif
        eoU[e] = make_uint2((unsigned)((y0c * W_ + xb_ + 1) * 128),
                            (unsigned)((y1c * W_ + xb_ + 1) * 128));
    }

    floatx4 acc[4];
    #pragma unroll
    for (int nt = 0; nt < 4; ++nt) acc[nt] = (floatx4){0.f, 0.f, 0.f, 0.f};

    __syncthreads();

    const int c2   = lane & 31;     // channel-pair index (channels 2c2, 2c2+1)
    const int c4   = c2 * 4;        // byte offset within the 128B row
    const int half = lane >> 5;     // 0/1: which pixel of the pair

    unsigned u[8][4];
    issue_tap_loads(xbB, eoU, 0, wq, half, c4, u);

    for (int t = 0; t < KK; ++t) {
        const int buf = t & 1;

        compute_tap(awP, &S[buf][0], t, wq, half, c2, u);
        __syncthreads();   // single barrier per tap (double-buffered S)

        // overlap MFMA(t) with next tap's gathers + A-frag prefetch
        short8 n0, n1;
        if (t < KK - 1) {
            issue_tap_loads(xbB, eoU, t + 1, wq, half, c4, u);
            n0 = wAv[abase + (8 * (t + 1)) * 64];
            n1 = wAv[abase + (8 * (t + 1) + 4) * 64];
        }

        {
            const int n = lane & 15;
            const int qk = (lane >> 4) * 8;
            #pragma unroll
            for (int nt = 0; nt < 4; ++nt) {
                int p = nt * 16 + n;
                short8 b0 = *(const short8*)&S[buf][p * SP + qk];        // ds_read_b128
                short8 b1 = *(const short8*)&S[buf][p * SP + 32 + qk];
                acc[nt] = __builtin_amdgcn_mfma_f32_16x16x32_bf16(a0, b0, acc[nt], 0, 0, 0);
                acc[nt] = __builtin_amdgcn_mfma_f32_16x16x32_bf16(a1, b1, acc[nt], 0, 0, 0);
            }
        }

        a0 = n0;   // slide the A window
        a1 = n1;
    }

    // ---- epilogue: + bias + x2, clip [0,6] ----
    // C/D layout: col = lane&15 (pixel), row = (lane>>4)*4 + reg (out channel)
    {
        const int n = lane & 15;
        const int orow = wq * 16 + (lane >> 4) * 4;
        float bia[4];
        #pragma unroll
        for (int reg = 0; reg < 4; ++reg) bia[reg] = bias[orow + reg];
        #pragma unroll
        for (int nt = 0; nt < 4; ++nt) {
            int hw = pix0 + nt * 16 + n;
            #pragma unroll
            for (int reg = 0; reg < 4; ++reg) {
                size_t idx = ((size_t)(b * COUT + orow + reg)) * HW + hw;
                float r = acc[nt][reg] + bia[reg] + x2[idx];
                r = fminf(fmaxf(r, 0.0f), 6.0f);
                out[idx] = r;
            }
        }
    }
}

// ---------- fallback (NCHW, fp32) if workspace too small ----------
__global__ __launch_bounds__(256, 4) void deform_nchw_kernel(
    const float* __restrict__ x, const float* __restrict__ offset,
    const float* __restrict__ x2, const float* __restrict__ weight,
    const float* __restrict__ bias, float* __restrict__ out)
{
    __shared__ float sT[CIN * PIX];
    __shared__ float ewS[4][KK * PIX];
    __shared__ int   eoS[4][KK * PIX];

    const int tid  = threadIdx.x;
    const int b    = blockIdx.x / BLKS_PER_B;
    const int pix0 = (blockIdx.x % BLKS_PER_B) * PIX;
    const int lane = tid & 63;
    const int wq   = __builtin_amdgcn_readfirstlane(tid >> 6);

    const float* xb   = x + (size_t)b * (CIN * HW);
    const float* offb = offset + (size_t)b * (18 * HW);

    for (int e = tid; e < KK * PIX; e += NTHR) {
        int k  = e >> 6;
        int p  = e & 63;
        int hw = pix0 + p;
        int h  = hw / W_;
        int w  = hw - h * W_;
        float offy = offb[(size_t)(2 * k) * HW + hw];
        float offx = offb[(size_t)(2 * k + 1) * HW + hw];
        int ki = k / 3;
        int kj = k - ki * 3;
        float yy = (float)(h - 1 + ki) + offy;
        float xx = (float)(w - 1 + kj) + offx;
        float y0f = floorf(yy), x0f = floorf(xx);
        float wy1 = yy - y0f, wx1 = xx - x0f;
        float wy0 = 1.0f - wy1, wx0 = 1.0f - wx1;
        int y0 = (int)y0f, x0 = (int)x0f;
        int y1 = y0 + 1, x1 = x0 + 1;
        float vy0 = (y0 >= 0 && y0 < H_) ? 1.0f : 0.0f;
        float vy1 = (y1 >= 0 && y1 < H_) ? 1.0f : 0.0f;
        float vx0 = (x0 >= 0 && x0 < W_) ? 1.0f : 0.0f;
        float vx1 = (x1 >= 0 && x1 < W_) ? 1.0f : 0.0f;
        int y0c = min(max(y0, 0), H_ - 1), y1c = min(max(y1, 0), H_ - 1);
        int x0c = min(max(x0, 0), W_ - 1), x1c = min(max(x1, 0), W_ - 1);
        ewS[0][e] = wy0 * wx0 * vy0 * vx0;
        ewS[1][e] = wy0 * wx1 * vy0 * vx1;
        ewS[2][e] = wy1 * wx0 * vy1 * vx0;
        ewS[3][e] = wy1 * wx1 * vy1 * vx1;
        eoS[0][e] = y0c * W_ + x0c;
        eoS[1][e] = y0c * W_ + x1c;
        eoS[2][e] = y1c * W_ + x0c;
        eoS[3][e] = y1c * W_ + x1c;
    }

    float acc[16];
    #pragma unroll
    for (int i = 0; i < 16; ++i) acc[i] = 0.0f;

    __syncthreads();

    for (int k = 0; k < KK; ++k) {
        {
            const int eb = k * 64 + lane;
            const float w0 = ewS[0][eb], w1 = ewS[1][eb], w2 = ewS[2][eb], w3 = ewS[3][eb];
            const int   o0 = eoS[0][eb], o1 = eoS[1][eb], o2 = eoS[2][eb], o3 = eoS[3][eb];
            const int cg = tid >> 6;
            const float* xc = xb + (size_t)(cg * 16) * HW;
            #pragma unroll
            for (int i = 0; i < 16; ++i) {
                float v = w0 * xc[o0] + w1 * xc[o1] + w2 * xc[o2] + w3 * xc[o3];
                sT[(cg * 16 + i) * 64 + lane] = v;
                xc += HW;
            }
        }
        __syncthreads();
        {
            #pragma unroll 2
            for (int c = 0; c < 64; ++c) {
                float sv = sT[c * 64 + lane];
                #pragma unroll
                for (int oi = 0; oi < 16; ++oi)
                    acc[oi] = fmaf(weight[(wq * 16 + oi) * 576 + c * 9 + k], sv, acc[oi]);
            }
        }
        __syncthreads();
    }

    const size_t obase = ((size_t)b * COUT + wq * 16) * HW + pix0 + lane;
    #pragma unroll
    for (int oi = 0; oi < 16; ++oi) {
        float r = acc[oi] + bias[wq * 16 + oi] + x2[obase + (size_t)oi * HW];
        r = fminf(fmaxf(r, 0.0f), 6.0f);
        out[obase + (size_t)oi * HW] = r;
    }
}

extern "C" void kernel_launch(void* const* d_in, const int* in_sizes, int n_in,
                              void* d_out, int out_size, void* d_ws, size_t ws_size,
                              hipStream_t stream) {
    const float* x      = (const float*)d_in[0];
    const float* offset = (const float*)d_in[1];
    const float* x2     = (const float*)d_in[2];
    const float* weight = (const float*)d_in[3];
    const float* bias   = (const float*)d_in[4];
    float* out          = (float*)d_out;

    const int grid = B_ * BLKS_PER_B;   // 1152 blocks

    const size_t xT_off   = 256;                                              // front pad for biased reads
    const size_t xT_bytes = (size_t)B_ * HW * CIN * sizeof(unsigned short);   // 9.44 MB
    const size_t wA_bytes = (size_t)18 * 4 * 64 * 8 * sizeof(unsigned short); // 73.7 KB

    if (ws_size >= xT_off + xT_bytes + wA_bytes) {
        unsigned int*   xTu = (unsigned int*)((char*)d_ws + xT_off);
        unsigned short* wA  = (unsigned short*)((char*)d_ws + xT_off + xT_bytes);
        prep_kernel<<<grid + 18, 256, 0, stream>>>(x, weight, xTu, wA);
        deform_mfma_kernel<<<grid, NTHR, 0, stream>>>(xTu, offset, x2, bias, wA, out);
    } else {
        deform_nchw_kernel<<<grid, NTHR, 0, stream>>>(x, offset, x2, weight, bias, out);
    }
}